// Round 15
// baseline (168.162 us; speedup 1.0000x reference)
//
#include <hip/hip_runtime.h>

// Problem constants
#define BB 2
#define SQ 2048
#define SK 2048
#define DD 1024
#define HH 16
#define HS 64
#define SCALE 0.125f
#define LOG2E 1.4426950408889634f

typedef __bf16 bf16x8 __attribute__((ext_vector_type(8)));
typedef float f32x4 __attribute__((ext_vector_type(4)));
typedef unsigned int uint;

// Fast hardware exp2 (exp2f without -ffast-math lowers to the ~20-instr OCML path)
#if defined(__has_builtin)
#if __has_builtin(__builtin_amdgcn_exp2f)
#define FEXP2(x) __builtin_amdgcn_exp2f(x)
#endif
#endif
#ifndef FEXP2
extern "C" __device__ float __ocml_native_exp2_f32(float);
#define FEXP2(x) __ocml_native_exp2_f32(x)
#endif

__device__ __forceinline__ void gload_lds16(const __bf16* g, __bf16* l) {
    __builtin_amdgcn_global_load_lds((const __attribute__((address_space(1))) uint*)(g),
                                     (__attribute__((address_space(3))) uint*)(l), 16, 0, 0);
}

// ------------- cast+transpose weights [K][N] -> bf16 [N][K], B-read swizzle baked in -------------
__global__ void wtrans(const float* __restrict__ W0, const float* __restrict__ W1,
                       const float* __restrict__ W2, const float* __restrict__ W3,
                       __bf16* __restrict__ Wt) {
    __shared__ __bf16 tile[32][33];
    const float* W = blockIdx.z == 0 ? W0 : blockIdx.z == 1 ? W1 : blockIdx.z == 2 ? W2 : W3;
    __bf16* out = Wt + (size_t)blockIdx.z * DD * DD;
    int tx = threadIdx.x, ty = threadIdx.y;     // (32, 8)
    int k0 = blockIdx.y * 32, n0 = blockIdx.x * 32;
#pragma unroll
    for (int j = 0; j < 4; ++j)
        tile[ty + j * 8][tx] = (__bf16)W[(size_t)(k0 + ty + j * 8) * DD + n0 + tx];
    __syncthreads();
#pragma unroll
    for (int j = 0; j < 4; ++j) {
        int n = n0 + ty + j * 8;
        int k = k0 + tx;
        int kswz = (k & ~63) | ((((k >> 3) ^ n) & 7) << 3) | (k & 7);
        out[(size_t)n * DD + kswz] = tile[tx][ty + j * 8];
    }
}

// ------------- unified QKV projection GEMM, 2-deep register prefetch -------------
// Two named staging reg sets (X/Y) ping-pong: loads for tile kt+128 issue at step kt, so
// the vmcnt wait at G_WRITE consumes loads ~2 step-times (~500+ cyc) old -> latency hidden.
// Loop unrolled x2 so set parity is compile-time (rule 20: no runtime-indexed reg arrays).
// Q-blocks: A=inputs vs 128 cols Wq. KV-blocks: A=context vs 64 cols Wk + 64 cols Wv
// (one A staging feeds BOTH outputs). acc[2][4], 16 MFMA/wave/kt-step.
__global__ __launch_bounds__(256, 4) void gemm_qkv(
        const float* __restrict__ Ain, const float* __restrict__ Actx,
        const __bf16* __restrict__ Wt,
        const float* __restrict__ bq, const float* __restrict__ bk, const float* __restrict__ bv,
        __bf16* __restrict__ Qb, __bf16* __restrict__ Kb, __bf16* __restrict__ Vtb,
        float qscale) {
    __shared__ __bf16 As[64][64];     // 8 KB
    __shared__ __bf16 Bs[128][64];    // 16 KB
    int t = threadIdx.x, w = t >> 6, l = t & 63;
    int lm = l & 15, lk = l >> 4;
    int wr = w >> 1, wc = w & 1;
    // T1 XCD swizzle over 1536 wgs (grid 16x96): each XCD gets 192 contiguous nf
    int flat = blockIdx.x + 16 * blockIdx.y;
    int nf = (flat & 7) * 192 + (flat >> 3);
    bool isQ = nf < 512;
    int bc, br;
    if (isQ) { bc = nf & 7; br = nf >> 3; }
    else     { int f = nf - 512; bc = f & 15; br = f >> 4; }

    // A staging geometry: row ra = t>>2, fp32 cols ca*8 .. ca*8+15 (two bf16x8 chunks)
    int ra = t >> 2, ca = (t & 3) * 2;
    const float* ag = (isQ ? Ain : Actx) + (size_t)(br * 64 + ra) * 1024 + ca * 8;
    __bf16* aw0 = &As[ra][((ca)     ^ (ra & 7)) * 8];
    __bf16* aw1 = &As[ra][((ca + 1) ^ (ra & 7)) * 8];

    // B staging geometry: rows rb, rb+32, rb+64, rb+96; chunk c8 (source pre-swizzled)
    int rb = t >> 3, c8 = t & 7;
    const __bf16 *bg0, *bg1, *bg2, *bg3;
    if (isQ) {
        const __bf16* Wq_ = Wt;
        bg0 = Wq_ + (size_t)(bc * 128 + rb)      * 1024 + c8 * 8;
        bg1 = Wq_ + (size_t)(bc * 128 + rb + 32) * 1024 + c8 * 8;
        bg2 = Wq_ + (size_t)(bc * 128 + rb + 64) * 1024 + c8 * 8;
        bg3 = Wq_ + (size_t)(bc * 128 + rb + 96) * 1024 + c8 * 8;
    } else {
        const __bf16* Wk_ = Wt + (size_t)DD * DD;
        const __bf16* Wv_ = Wt + (size_t)2 * DD * DD;
        bg0 = Wk_ + (size_t)(bc * 64 + rb)      * 1024 + c8 * 8;
        bg1 = Wk_ + (size_t)(bc * 64 + rb + 32) * 1024 + c8 * 8;
        bg2 = Wv_ + (size_t)(bc * 64 + rb)      * 1024 + c8 * 8;
        bg3 = Wv_ + (size_t)(bc * 64 + rb + 32) * 1024 + c8 * 8;
    }
    __bf16* bw0 = &Bs[rb][c8 * 8];
    __bf16* bw1 = &Bs[rb + 32][c8 * 8];
    __bf16* bw2 = &Bs[rb + 64][c8 * 8];
    __bf16* bw3 = &Bs[rb + 96][c8 * 8];

    int brow[4];
#pragma unroll
    for (int n = 0; n < 4; ++n)
        brow[n] = isQ ? (wc * 64 + n * 16 + lm)
                      : ((n >> 1) * 64 + wc * 32 + (n & 1) * 16 + lm);

    // two NAMED staging sets (X and Y) -- 2-deep prefetch
    float4 xa0, xa1, xa2, xa3, xb0, xb1, xb2, xb3;
    float4 ya0, ya1, ya2, ya3, yb0, yb1, yb2, yb3;
#define G_LOADX()                                                                     \
    xa0 = *(const float4*)(ag);     xa1 = *(const float4*)(ag + 4);                   \
    xa2 = *(const float4*)(ag + 8); xa3 = *(const float4*)(ag + 12);                  \
    xb0 = *(const float4*)bg0; xb1 = *(const float4*)bg1;                             \
    xb2 = *(const float4*)bg2; xb3 = *(const float4*)bg3;                             \
    ag += 64; bg0 += 64; bg1 += 64; bg2 += 64; bg3 += 64;
#define G_LOADY()                                                                     \
    ya0 = *(const float4*)(ag);     ya1 = *(const float4*)(ag + 4);                   \
    ya2 = *(const float4*)(ag + 8); ya3 = *(const float4*)(ag + 12);                  \
    yb0 = *(const float4*)bg0; yb1 = *(const float4*)bg1;                             \
    yb2 = *(const float4*)bg2; yb3 = *(const float4*)bg3;                             \
    ag += 64; bg0 += 64; bg1 += 64; bg2 += 64; bg3 += 64;
#define G_WRITE(A0, A1, A2, A3, B0, B1, B2, B3)                                       \
    {                                                                                 \
        bf16x8 va0 = {(__bf16)A0.x, (__bf16)A0.y, (__bf16)A0.z, (__bf16)A0.w,         \
                      (__bf16)A1.x, (__bf16)A1.y, (__bf16)A1.z, (__bf16)A1.w};        \
        bf16x8 va1 = {(__bf16)A2.x, (__bf16)A2.y, (__bf16)A2.z, (__bf16)A2.w,         \
                      (__bf16)A3.x, (__bf16)A3.y, (__bf16)A3.z, (__bf16)A3.w};        \
        *(bf16x8*)aw0 = va0; *(bf16x8*)aw1 = va1;                                     \
        *(float4*)bw0 = B0; *(float4*)bw1 = B1;                                       \
        *(float4*)bw2 = B2; *(float4*)bw3 = B3;                                       \
    }

    f32x4 acc[2][4] = {};
    auto mfma_block = [&]() {
#pragma unroll
        for (int kk = 0; kk < 64; kk += 32) {
            int ch = ((kk >> 3) + lk);
            bf16x8 af[2], bf[4];
#pragma unroll
            for (int m = 0; m < 2; ++m)
                af[m] = *(const bf16x8*)&As[wr * 32 + m * 16 + lm][(ch ^ (lm & 7)) * 8];
#pragma unroll
            for (int n = 0; n < 4; ++n)
                bf[n] = *(const bf16x8*)&Bs[brow[n]][(ch ^ (lm & 7)) * 8];
#pragma unroll
            for (int m = 0; m < 2; ++m)
#pragma unroll
                for (int n = 0; n < 4; ++n)
                    acc[m][n] = __builtin_amdgcn_mfma_f32_16x16x32_bf16(af[m], bf[n], acc[m][n], 0, 0, 0);
        }
    };

    G_LOADX();            // tile 0
    G_LOADY();            // tile 1
    for (int kt = 0; kt < 1024; kt += 128) {
        // step A: tile kt (set X)
        __syncthreads();
        G_WRITE(xa0, xa1, xa2, xa3, xb0, xb1, xb2, xb3);
        __syncthreads();
        if (kt + 128 < 1024) { G_LOADX(); }      // tile kt+128, consumed 2 steps later
        mfma_block();
        // step B: tile kt+64 (set Y)
        __syncthreads();
        G_WRITE(ya0, ya1, ya2, ya3, yb0, yb1, yb2, yb3);
        __syncthreads();
        if (kt + 192 < 1024) { G_LOADY(); }      // tile kt+192
        mfma_block();
    }
#undef G_LOADX
#undef G_LOADY
#undef G_WRITE

    if (isQ) {
#pragma unroll
        for (int m = 0; m < 2; ++m)
#pragma unroll
            for (int n = 0; n < 4; ++n) {
                int col = bc * 128 + wc * 64 + n * 16 + lm;
                float bb = bq[col];
#pragma unroll
                for (int r = 0; r < 4; ++r) {
                    int row = br * 64 + wr * 32 + m * 16 + lk * 4 + r;
                    Qb[(size_t)row * 1024 + col] = (__bf16)((acc[m][n][r] + bb) * qscale);
                }
            }
    } else {
#pragma unroll
        for (int m = 0; m < 2; ++m)
#pragma unroll
            for (int n = 0; n < 4; ++n) {
                int col = bc * 64 + wc * 32 + (n & 1) * 16 + lm;
                if (n < 2) {
                    float bb = bk[col];
#pragma unroll
                    for (int r = 0; r < 4; ++r) {
                        int row = br * 64 + wr * 32 + m * 16 + lk * 4 + r;
                        Kb[(size_t)row * 1024 + col] = (__bf16)(acc[m][n][r] + bb);
                    }
                } else {
                    // Vt value for key-pos sk stored at sigma-permuted position:
                    // within 64-block: p = o5<<5 | o3<<4 | o2<<3 | o4<<2 (quad base)
                    float bb = bv[col];
                    int row = br * 64 + wr * 32 + m * 16 + lk * 4;   // sk quad base
                    int b_ = row >> 11, sk = row & 2047;
                    int skb = sk & ~63, o = sk & 63;
                    int p0 = (o & 32) | (((o >> 3) & 1) << 4) | (((o >> 2) & 1) << 3) | (((o >> 4) & 1) << 2);
                    int h_ = col >> 6, d_ = col & 63;
                    union { ushort4 u; __bf16 hh[4]; } pk;
#pragma unroll
                    for (int r = 0; r < 4; ++r) pk.hh[r] = (__bf16)(acc[m][n][r] + bb);
                    *(ushort4*)(Vtb + ((size_t)((b_ * 16 + h_) * 64 + d_) * 2048 + skb + p0)) = pk.u;
                }
            }
    }
}

// ------------- output GEMM: 64x128 tile, float out, T1 XCD swizzle -------------
// B (Wo) is pre-swizzled in global -> B reads use swizzled chunk; A (attb) linear.
__global__ __launch_bounds__(256) void gemm_out64(const __bf16* __restrict__ A, const __bf16* __restrict__ Bt,
                                                  const float* __restrict__ bias, float* __restrict__ C) {
    __shared__ __bf16 As[64][64];
    __shared__ __bf16 Bs[128][64];
    int t = threadIdx.x;
    int w = t >> 6, l = t & 63;
    int lm = l & 15, lk = l >> 4;
    // T1: grid (8,64) = 512 wgs -> XCD gets 8 br x 8 bc
    int flat = blockIdx.x + 8 * blockIdx.y;
    int nf = (flat & 7) * 64 + (flat >> 3);
    int bc = nf & 7, br = nf >> 3;
    int srow = (l >> 3), scol = (l & 7) * 8;
    f32x4 acc[4][2] = {};
    for (int kt = 0; kt < 1024; kt += 64) {
        __syncthreads();
#pragma unroll
        for (int j = 0; j < 2; ++j) {
            int r0 = (j * 4 + w) * 8;
            gload_lds16(&A[(size_t)(br * 64 + r0 + srow) * 1024 + kt + scol], &As[r0][0]);
        }
#pragma unroll
        for (int j = 0; j < 4; ++j) {
            int r0 = (j * 4 + w) * 8;
            gload_lds16(&Bt[(size_t)(bc * 128 + r0 + srow) * 1024 + kt + scol], &Bs[r0][0]);
        }
        __syncthreads();
#pragma unroll
        for (int kk = 0; kk < 64; kk += 32) {
            int ch = ((kk >> 3) + lk);
            bf16x8 af[4], bf[2];
#pragma unroll
            for (int m = 0; m < 4; ++m) af[m] = *(const bf16x8*)&As[m * 16 + lm][kk + lk * 8];
#pragma unroll
            for (int n = 0; n < 2; ++n)
                bf[n] = *(const bf16x8*)&Bs[w * 32 + n * 16 + lm][(ch ^ (lm & 7)) * 8];
#pragma unroll
            for (int m = 0; m < 4; ++m)
#pragma unroll
                for (int n = 0; n < 2; ++n)
                    acc[m][n] = __builtin_amdgcn_mfma_f32_16x16x32_bf16(af[m], bf[n], acc[m][n], 0, 0, 0);
        }
    }
#pragma unroll
    for (int m = 0; m < 4; ++m)
#pragma unroll
        for (int n = 0; n < 2; ++n) {
            int col = bc * 128 + w * 32 + n * 16 + lm;
            float bv = bias[col];
#pragma unroll
            for (int r = 0; r < 4; ++r) {
                int row = br * 64 + m * 16 + lk * 4 + r;
                C[(size_t)row * 1024 + col] = acc[m][n][r] + bv;
            }
        }
}

// ------------- flash attention, swapped-QK^T (S^T), lane-local P -------------
// 8 waves x 16 q-rows (512 threads, QBLK=128); KVBLK=64, double-buffered K/V, 1 barrier/tile.
// V's kv-permutation sigma baked into Vt's GLOBAL layout (gemm_qkv).
// Hoisted addressing; advancing global pointers; ones-MFMA row-sums; HW exp2; T1 swizzle.
__global__ __launch_bounds__(512) void flash_attn(const __bf16* __restrict__ Q,
                                                  const __bf16* __restrict__ Kb,
                                                  const __bf16* __restrict__ Vt,
                                                  __bf16* __restrict__ O) {
    __shared__ __bf16 Ks[2][64 * 64];
    __shared__ __bf16 Vs[2][64 * 64];
    int t = threadIdx.x, w = t >> 6, l = t & 63;
    int lm = l & 15, lk = l >> 4;
    // T1: grid (16,32) = 512 wgs -> XCD gets 4 bh x 16 q-tiles (KV panels L2-resident)
    int flat = blockIdx.x + 16 * blockIdx.y;
    int nf = (flat & 7) * 64 + (flat >> 3);
    int bh = nf >> 4, b = bh >> 4, h = bh & 15;
    int q0 = (nf & 15) * 128;

    // Q fragments straight from global (one-time): wave w owns q rows q0+w*16 .. +15
    bf16x8 qf[2];
#pragma unroll
    for (int kk = 0; kk < 2; ++kk)
        qf[kk] = *(const bf16x8*)&Q[(size_t)(b * SQ + q0 + w * 16 + lm) * DD + h * HS + kk * 32 + lk * 8];

    // staging geometry: 512 threads cover the 64x64 tile once: row r0 = t>>3, chunk c8 = t&7
    int r0 = t >> 3, c8 = t & 7;
    int chs = c8 ^ (r0 & 7);
    __bf16* ksl0 = &Ks[0][r0 * 64 + chs * 8];
    __bf16* vsl0 = &Vs[0][r0 * 64 + chs * 8];

    // advancing global pointers (K: +64 rows/tile; V: +64 cols/tile)
    const __bf16* kp0 = Kb + (size_t)b * SK * DD + h * HS + (size_t)r0 * DD + c8 * 8;
    const __bf16* vp0 = Vt + (size_t)bh * HS * SK + (size_t)r0 * SK + c8 * 8;

    // per-lane swizzled LDS read offsets (elements): row term lm*64 folded in
    int o0 = lm * 64 + ((lk ^ (lm & 7)) * 8);
    int o1 = lm * 64 + (((4 + lk) ^ (lm & 7)) * 8);

    float4 kr0, vr0;   // NAMED regs only (arrays -> scratch)
#define FA_LOAD()                                                                \
    kr0 = *(const float4*)kp0; vr0 = *(const float4*)vp0;                        \
    kp0 += (size_t)64 * DD; vp0 += 64;
#define FA_WRITE(BUF)                                                            \
    *(float4*)(ksl0 + (BUF) * 4096) = kr0;                                       \
    *(float4*)(vsl0 + (BUF) * 4096) = vr0;

    FA_LOAD();
    FA_WRITE(0);
    __syncthreads();

    bf16x8 ones;
#pragma unroll
    for (int j = 0; j < 8; ++j) ones[j] = (__bf16)1.0f;

    f32x4 o[4] = {};
    f32x4 o_s = {};

    for (int it = 0; it < 32; ++it) {
        int buf = it & 1;
        if (it + 1 < 32) { FA_LOAD(); }   // issue early; hides under compute

        const __bf16* KsB = &Ks[buf][0];
        const __bf16* VsB = &Vs[buf][0];

        // S^T = K Q^T : st[n], lane holds P[q=w*16+lm][kv=16n+4lk+r]
        f32x4 st[4] = {};
        __builtin_amdgcn_s_setprio(1);
#pragma unroll
        for (int kk = 0; kk < 2; ++kk) {
#pragma unroll
            for (int n = 0; n < 4; ++n) {
                bf16x8 kf = *(const bf16x8*)&KsB[(kk ? o1 : o0) + n * 1024];
                st[n] = __builtin_amdgcn_mfma_f32_16x16x32_bf16(kf, qf[kk], st[n], 0, 0, 0);
            }
        }
        __builtin_amdgcn_s_setprio(0);

        // P = exp2(S) fused into fragment assembly; PV + ones-column row-sum
#pragma unroll
        for (int kk = 0; kk < 2; ++kk) {
            bf16x8 pa;
#pragma unroll
            for (int j = 0; j < 8; ++j)
                pa[j] = (__bf16)FEXP2(st[2 * kk + (j >> 2)][j & 3]);
            __builtin_amdgcn_s_setprio(1);
            o_s = __builtin_amdgcn_mfma_f32_16x16x32_bf16(pa, ones, o_s, 0, 0, 0);
#pragma unroll
            for (int dn = 0; dn < 4; ++dn) {
                bf16x8 vf = *(const bf16x8*)&VsB[(kk ? o1 : o0) + dn * 1024];
                o[dn] = __builtin_amdgcn_mfma_f32_16x16x32_bf16(pa, vf, o[dn], 0, 0, 0);
            }
            __builtin_amdgcn_s_setprio(0);
        }

        if (it + 1 < 32) { FA_WRITE(buf ^ 1); }        // lands in the other buffer
        __syncthreads();                               // one barrier per tile
    }

    // epilogue: o_s[r] holds rowsum(q = w*16 + lk*4 + r) at every lm lane
    f32x4 inv;
#pragma unroll
    for (int r = 0; r < 4; ++r) inv[r] = 1.f / o_s[r];
#pragma unroll
    for (int dn = 0; dn < 4; ++dn)
#pragma unroll
        for (int r = 0; r < 4; ++r) {
            int row = q0 + w * 16 + lk * 4 + r;
            int col = h * HS + dn * 16 + lm;
            O[(size_t)(b * SQ + row) * DD + col] = (__bf16)(o[dn][r] * inv[r]);
        }
}

extern "C" void kernel_launch(void* const* d_in, const int* in_sizes, int n_in,
                              void* d_out, int out_size, void* d_ws, size_t ws_size,
                              hipStream_t stream) {
    const float* inputs  = (const float*)d_in[0];
    const float* context = (const float*)d_in[1];
    const float* Wq = (const float*)d_in[2];
    const float* bq = (const float*)d_in[3];
    const float* Wk = (const float*)d_in[4];
    const float* bk = (const float*)d_in[5];
    const float* Wv = (const float*)d_in[6];
    const float* bv = (const float*)d_in[7];
    const float* Wo = (const float*)d_in[8];
    const float* bo = (const float*)d_in[9];
    float* out = (float*)d_out;

    char* ws = (char*)d_ws;
    const size_t SEG = (size_t)4096 * 1024 * sizeof(__bf16);  // 8 MB
    __bf16* attb = (__bf16*)(ws + 0 * SEG);   // attention output (bf16)
    __bf16* Wt   = (__bf16*)(ws + 2 * SEG);   // 4 x 1024x1024 bf16 (B-swizzled layout)
    __bf16* Qb   = (__bf16*)(ws + 3 * SEG);
    __bf16* Kbuf = (__bf16*)(ws + 4 * SEG);
    __bf16* Vtb  = (__bf16*)(ws + 5 * SEG);   // V transposed + sigma-permuted by gemm_qkv

    wtrans<<<dim3(32, 32, 4), dim3(32, 8), 0, stream>>>(Wq, Wk, Wv, Wo, Wt);

    gemm_qkv<<<dim3(16, 96), 256, 0, stream>>>(inputs, context, Wt, bq, bk, bv,
                                               Qb, Kbuf, Vtb, SCALE * LOG2E);

    flash_attn<<<dim3(16, 32), 512, 0, stream>>>(Qb, Kbuf, Vtb, attb);

    gemm_out64<<<dim3(8, 64), 256, 0, stream>>>(attb, Wt + (size_t)3 * DD * DD, bo, out);
}

// Round 16
// 117.426 us; speedup vs baseline: 1.4321x; 1.4321x over previous
//
#include <hip/hip_runtime.h>

// Problem constants
#define BB 2
#define SQ 2048
#define SK 2048
#define DD 1024
#define HH 16
#define HS 64
#define SCALE 0.125f
#define LOG2E 1.4426950408889634f

typedef __bf16 bf16x8 __attribute__((ext_vector_type(8)));
typedef float f32x4 __attribute__((ext_vector_type(4)));
typedef unsigned int uint;

// Fast hardware exp2 (exp2f without -ffast-math lowers to the ~20-instr OCML path)
#if defined(__has_builtin)
#if __has_builtin(__builtin_amdgcn_exp2f)
#define FEXP2(x) __builtin_amdgcn_exp2f(x)
#endif
#endif
#ifndef FEXP2
extern "C" __device__ float __ocml_native_exp2_f32(float);
#define FEXP2(x) __ocml_native_exp2_f32(x)
#endif

__device__ __forceinline__ void gload_lds16(const __bf16* g, __bf16* l) {
    __builtin_amdgcn_global_load_lds((const __attribute__((address_space(1))) uint*)(g),
                                     (__attribute__((address_space(3))) uint*)(l), 16, 0, 0);
}

// ------------- cast+transpose weights [K][N] -> bf16 [N][K], B-read swizzle baked in -------------
__global__ void wtrans(const float* __restrict__ W0, const float* __restrict__ W1,
                       const float* __restrict__ W2, const float* __restrict__ W3,
                       __bf16* __restrict__ Wt) {
    __shared__ __bf16 tile[32][33];
    const float* W = blockIdx.z == 0 ? W0 : blockIdx.z == 1 ? W1 : blockIdx.z == 2 ? W2 : W3;
    __bf16* out = Wt + (size_t)blockIdx.z * DD * DD;
    int tx = threadIdx.x, ty = threadIdx.y;     // (32, 8)
    int k0 = blockIdx.y * 32, n0 = blockIdx.x * 32;
#pragma unroll
    for (int j = 0; j < 4; ++j)
        tile[ty + j * 8][tx] = (__bf16)W[(size_t)(k0 + ty + j * 8) * DD + n0 + tx];
    __syncthreads();
#pragma unroll
    for (int j = 0; j < 4; ++j) {
        int n = n0 + ty + j * 8;
        int k = k0 + tx;
        int kswz = (k & ~63) | ((((k >> 3) ^ n) & 7) << 3) | (k & 7);
        out[(size_t)n * DD + kswz] = tile[tx][ty + j * 8];
    }
}

// ------------- unified QKV projection GEMM, flash-style 1-barrier double-buffered LDS -------------
// Per step: issue next tile's global loads (regs) -> MFMA on buf -> write buf^1 (vmcnt wait
// lands AFTER a full compute phase -> latency covered) -> ONE barrier. Single staging reg set
// (round-15 lesson: two sets spill past the reg cap). LDS 48 KB -> 3 blocks/CU.
// Q-blocks: A=inputs vs 128 cols Wq. KV-blocks: A=context vs 64 cols Wk + 64 cols Wv
// (one A staging feeds BOTH outputs). acc[2][4], 16 MFMA/wave/kt-step.
__global__ __launch_bounds__(256, 3) void gemm_qkv(
        const float* __restrict__ Ain, const float* __restrict__ Actx,
        const __bf16* __restrict__ Wt,
        const float* __restrict__ bq, const float* __restrict__ bk, const float* __restrict__ bv,
        __bf16* __restrict__ Qb, __bf16* __restrict__ Kb, __bf16* __restrict__ Vtb,
        float qscale) {
    __shared__ __bf16 As[2 * 64 * 64];    // 16 KB (double-buffered)
    __shared__ __bf16 Bs[2 * 128 * 64];   // 32 KB (double-buffered)
    int t = threadIdx.x, w = t >> 6, l = t & 63;
    int lm = l & 15, lk = l >> 4;
    int wr = w >> 1, wc = w & 1;
    // T1 XCD swizzle over 1536 wgs (grid 16x96): each XCD gets 192 contiguous nf
    int flat = blockIdx.x + 16 * blockIdx.y;
    int nf = (flat & 7) * 192 + (flat >> 3);
    bool isQ = nf < 512;
    int bc, br;
    if (isQ) { bc = nf & 7; br = nf >> 3; }
    else     { int f = nf - 512; bc = f & 15; br = f >> 4; }

    // A staging geometry: row ra = t>>2, fp32 cols ca*8 .. ca*8+15 (two bf16x8 chunks)
    int ra = t >> 2, ca = (t & 3) * 2;
    const float* ag = (isQ ? Ain : Actx) + (size_t)(br * 64 + ra) * 1024 + ca * 8;
    __bf16* aw0 = &As[ra * 64 + ((ca)     ^ (ra & 7)) * 8];
    __bf16* aw1 = &As[ra * 64 + ((ca + 1) ^ (ra & 7)) * 8];

    // B staging geometry: rows rb, rb+32, rb+64, rb+96; chunk c8 (source pre-swizzled)
    int rb = t >> 3, c8 = t & 7;
    const __bf16 *bg0, *bg1, *bg2, *bg3;
    if (isQ) {
        const __bf16* Wq_ = Wt;
        bg0 = Wq_ + (size_t)(bc * 128 + rb)      * 1024 + c8 * 8;
        bg1 = Wq_ + (size_t)(bc * 128 + rb + 32) * 1024 + c8 * 8;
        bg2 = Wq_ + (size_t)(bc * 128 + rb + 64) * 1024 + c8 * 8;
        bg3 = Wq_ + (size_t)(bc * 128 + rb + 96) * 1024 + c8 * 8;
    } else {
        const __bf16* Wk_ = Wt + (size_t)DD * DD;
        const __bf16* Wv_ = Wt + (size_t)2 * DD * DD;
        bg0 = Wk_ + (size_t)(bc * 64 + rb)      * 1024 + c8 * 8;
        bg1 = Wk_ + (size_t)(bc * 64 + rb + 32) * 1024 + c8 * 8;
        bg2 = Wv_ + (size_t)(bc * 64 + rb)      * 1024 + c8 * 8;
        bg3 = Wv_ + (size_t)(bc * 64 + rb + 32) * 1024 + c8 * 8;
    }
    __bf16* bw0 = &Bs[(rb)      * 64 + c8 * 8];
    __bf16* bw1 = &Bs[(rb + 32) * 64 + c8 * 8];
    __bf16* bw2 = &Bs[(rb + 64) * 64 + c8 * 8];
    __bf16* bw3 = &Bs[(rb + 96) * 64 + c8 * 8];

    int brow[4];
#pragma unroll
    for (int n = 0; n < 4; ++n)
        brow[n] = isQ ? (wc * 64 + n * 16 + lm)
                      : ((n >> 1) * 64 + wc * 32 + (n & 1) * 16 + lm);

    float4 xa0, xa1, xa2, xa3, xb0, xb1, xb2, xb3;   // single NAMED staging set
#define G_LOAD()                                                                      \
    xa0 = *(const float4*)(ag);     xa1 = *(const float4*)(ag + 4);                   \
    xa2 = *(const float4*)(ag + 8); xa3 = *(const float4*)(ag + 12);                  \
    xb0 = *(const float4*)bg0; xb1 = *(const float4*)bg1;                             \
    xb2 = *(const float4*)bg2; xb3 = *(const float4*)bg3;                             \
    ag += 64; bg0 += 64; bg1 += 64; bg2 += 64; bg3 += 64;
#define G_WRITE(BUF)                                                                  \
    {                                                                                 \
        bf16x8 va0 = {(__bf16)xa0.x, (__bf16)xa0.y, (__bf16)xa0.z, (__bf16)xa0.w,     \
                      (__bf16)xa1.x, (__bf16)xa1.y, (__bf16)xa1.z, (__bf16)xa1.w};    \
        bf16x8 va1 = {(__bf16)xa2.x, (__bf16)xa2.y, (__bf16)xa2.z, (__bf16)xa2.w,     \
                      (__bf16)xa3.x, (__bf16)xa3.y, (__bf16)xa3.z, (__bf16)xa3.w};    \
        *(bf16x8*)(aw0 + (BUF) * 4096) = va0;                                         \
        *(bf16x8*)(aw1 + (BUF) * 4096) = va1;                                         \
        *(float4*)(bw0 + (BUF) * 8192) = xb0;                                         \
        *(float4*)(bw1 + (BUF) * 8192) = xb1;                                         \
        *(float4*)(bw2 + (BUF) * 8192) = xb2;                                         \
        *(float4*)(bw3 + (BUF) * 8192) = xb3;                                         \
    }

    f32x4 acc[2][4] = {};
    G_LOAD();
    G_WRITE(0);
    __syncthreads();
    for (int kt = 0; kt < 1024; kt += 64) {
        int buf = (kt >> 6) & 1;
        bool more = (kt + 64 < 1024);
        if (more) { G_LOAD(); }                 // issue next tile's loads (regs)
#pragma unroll
        for (int kk = 0; kk < 64; kk += 32) {
            int ch = ((kk >> 3) + lk);
            bf16x8 af[2], bf[4];
#pragma unroll
            for (int m = 0; m < 2; ++m)
                af[m] = *(const bf16x8*)&As[buf * 4096 + (wr * 32 + m * 16 + lm) * 64 + (ch ^ (lm & 7)) * 8];
#pragma unroll
            for (int n = 0; n < 4; ++n)
                bf[n] = *(const bf16x8*)&Bs[buf * 8192 + brow[n] * 64 + (ch ^ (lm & 7)) * 8];
#pragma unroll
            for (int m = 0; m < 2; ++m)
#pragma unroll
                for (int n = 0; n < 4; ++n)
                    acc[m][n] = __builtin_amdgcn_mfma_f32_16x16x32_bf16(af[m], bf[n], acc[m][n], 0, 0, 0);
        }
        if (more) { G_WRITE(buf ^ 1); }         // vmcnt wait lands after full compute phase
        __syncthreads();                        // one barrier per step
    }
#undef G_LOAD
#undef G_WRITE

    if (isQ) {
#pragma unroll
        for (int m = 0; m < 2; ++m)
#pragma unroll
            for (int n = 0; n < 4; ++n) {
                int col = bc * 128 + wc * 64 + n * 16 + lm;
                float bb = bq[col];
#pragma unroll
                for (int r = 0; r < 4; ++r) {
                    int row = br * 64 + wr * 32 + m * 16 + lk * 4 + r;
                    Qb[(size_t)row * 1024 + col] = (__bf16)((acc[m][n][r] + bb) * qscale);
                }
            }
    } else {
#pragma unroll
        for (int m = 0; m < 2; ++m)
#pragma unroll
            for (int n = 0; n < 4; ++n) {
                int col = bc * 64 + wc * 32 + (n & 1) * 16 + lm;
                if (n < 2) {
                    float bb = bk[col];
#pragma unroll
                    for (int r = 0; r < 4; ++r) {
                        int row = br * 64 + wr * 32 + m * 16 + lk * 4 + r;
                        Kb[(size_t)row * 1024 + col] = (__bf16)(acc[m][n][r] + bb);
                    }
                } else {
                    // Vt value for key-pos sk stored at sigma-permuted position:
                    // within 64-block: p = o5<<5 | o3<<4 | o2<<3 | o4<<2 (quad base)
                    float bb = bv[col];
                    int row = br * 64 + wr * 32 + m * 16 + lk * 4;   // sk quad base
                    int b_ = row >> 11, sk = row & 2047;
                    int skb = sk & ~63, o = sk & 63;
                    int p0 = (o & 32) | (((o >> 3) & 1) << 4) | (((o >> 2) & 1) << 3) | (((o >> 4) & 1) << 2);
                    int h_ = col >> 6, d_ = col & 63;
                    union { ushort4 u; __bf16 hh[4]; } pk;
#pragma unroll
                    for (int r = 0; r < 4; ++r) pk.hh[r] = (__bf16)(acc[m][n][r] + bb);
                    *(ushort4*)(Vtb + ((size_t)((b_ * 16 + h_) * 64 + d_) * 2048 + skb + p0)) = pk.u;
                }
            }
    }
}

// ------------- output GEMM: 64x128 tile, float out, T1 XCD swizzle -------------
// B (Wo) is pre-swizzled in global -> B reads use swizzled chunk; A (attb) linear.
__global__ __launch_bounds__(256) void gemm_out64(const __bf16* __restrict__ A, const __bf16* __restrict__ Bt,
                                                  const float* __restrict__ bias, float* __restrict__ C) {
    __shared__ __bf16 As[64][64];
    __shared__ __bf16 Bs[128][64];
    int t = threadIdx.x;
    int w = t >> 6, l = t & 63;
    int lm = l & 15, lk = l >> 4;
    // T1: grid (8,64) = 512 wgs -> XCD gets 8 br x 8 bc
    int flat = blockIdx.x + 8 * blockIdx.y;
    int nf = (flat & 7) * 64 + (flat >> 3);
    int bc = nf & 7, br = nf >> 3;
    int srow = (l >> 3), scol = (l & 7) * 8;
    f32x4 acc[4][2] = {};
    for (int kt = 0; kt < 1024; kt += 64) {
        __syncthreads();
#pragma unroll
        for (int j = 0; j < 2; ++j) {
            int r0 = (j * 4 + w) * 8;
            gload_lds16(&A[(size_t)(br * 64 + r0 + srow) * 1024 + kt + scol], &As[r0][0]);
        }
#pragma unroll
        for (int j = 0; j < 4; ++j) {
            int r0 = (j * 4 + w) * 8;
            gload_lds16(&Bt[(size_t)(bc * 128 + r0 + srow) * 1024 + kt + scol], &Bs[r0][0]);
        }
        __syncthreads();
#pragma unroll
        for (int kk = 0; kk < 64; kk += 32) {
            int ch = ((kk >> 3) + lk);
            bf16x8 af[4], bf[2];
#pragma unroll
            for (int m = 0; m < 4; ++m) af[m] = *(const bf16x8*)&As[m * 16 + lm][kk + lk * 8];
#pragma unroll
            for (int n = 0; n < 2; ++n)
                bf[n] = *(const bf16x8*)&Bs[w * 32 + n * 16 + lm][(ch ^ (lm & 7)) * 8];
#pragma unroll
            for (int m = 0; m < 4; ++m)
#pragma unroll
                for (int n = 0; n < 2; ++n)
                    acc[m][n] = __builtin_amdgcn_mfma_f32_16x16x32_bf16(af[m], bf[n], acc[m][n], 0, 0, 0);
        }
    }
#pragma unroll
    for (int m = 0; m < 4; ++m)
#pragma unroll
        for (int n = 0; n < 2; ++n) {
            int col = bc * 128 + w * 32 + n * 16 + lm;
            float bv = bias[col];
#pragma unroll
            for (int r = 0; r < 4; ++r) {
                int row = br * 64 + m * 16 + lk * 4 + r;
                C[(size_t)row * 1024 + col] = acc[m][n][r] + bv;
            }
        }
}

// ------------- flash attention, swapped-QK^T (S^T), lane-local P -------------
// 8 waves x 16 q-rows (512 threads, QBLK=128); KVBLK=64, double-buffered K/V, 1 barrier/tile.
// V's kv-permutation sigma baked into Vt's GLOBAL layout (gemm_qkv).
// Hoisted addressing; advancing global pointers; ones-MFMA row-sums; HW exp2; T1 swizzle.
__global__ __launch_bounds__(512) void flash_attn(const __bf16* __restrict__ Q,
                                                  const __bf16* __restrict__ Kb,
                                                  const __bf16* __restrict__ Vt,
                                                  __bf16* __restrict__ O) {
    __shared__ __bf16 Ks[2][64 * 64];
    __shared__ __bf16 Vs[2][64 * 64];
    int t = threadIdx.x, w = t >> 6, l = t & 63;
    int lm = l & 15, lk = l >> 4;
    // T1: grid (16,32) = 512 wgs -> XCD gets 4 bh x 16 q-tiles (KV panels L2-resident)
    int flat = blockIdx.x + 16 * blockIdx.y;
    int nf = (flat & 7) * 64 + (flat >> 3);
    int bh = nf >> 4, b = bh >> 4, h = bh & 15;
    int q0 = (nf & 15) * 128;

    // Q fragments straight from global (one-time): wave w owns q rows q0+w*16 .. +15
    bf16x8 qf[2];
#pragma unroll
    for (int kk = 0; kk < 2; ++kk)
        qf[kk] = *(const bf16x8*)&Q[(size_t)(b * SQ + q0 + w * 16 + lm) * DD + h * HS + kk * 32 + lk * 8];

    // staging geometry: 512 threads cover the 64x64 tile once: row r0 = t>>3, chunk c8 = t&7
    int r0 = t >> 3, c8 = t & 7;
    int chs = c8 ^ (r0 & 7);
    __bf16* ksl0 = &Ks[0][r0 * 64 + chs * 8];
    __bf16* vsl0 = &Vs[0][r0 * 64 + chs * 8];

    // advancing global pointers (K: +64 rows/tile; V: +64 cols/tile)
    const __bf16* kp0 = Kb + (size_t)b * SK * DD + h * HS + (size_t)r0 * DD + c8 * 8;
    const __bf16* vp0 = Vt + (size_t)bh * HS * SK + (size_t)r0 * SK + c8 * 8;

    // per-lane swizzled LDS read offsets (elements): row term lm*64 folded in
    int o0 = lm * 64 + ((lk ^ (lm & 7)) * 8);
    int o1 = lm * 64 + (((4 + lk) ^ (lm & 7)) * 8);

    float4 kr0, vr0;   // NAMED regs only (arrays -> scratch)
#define FA_LOAD()                                                                \
    kr0 = *(const float4*)kp0; vr0 = *(const float4*)vp0;                        \
    kp0 += (size_t)64 * DD; vp0 += 64;
#define FA_WRITE(BUF)                                                            \
    *(float4*)(ksl0 + (BUF) * 4096) = kr0;                                       \
    *(float4*)(vsl0 + (BUF) * 4096) = vr0;

    FA_LOAD();
    FA_WRITE(0);
    __syncthreads();

    bf16x8 ones;
#pragma unroll
    for (int j = 0; j < 8; ++j) ones[j] = (__bf16)1.0f;

    f32x4 o[4] = {};
    f32x4 o_s = {};

    for (int it = 0; it < 32; ++it) {
        int buf = it & 1;
        if (it + 1 < 32) { FA_LOAD(); }   // issue early; hides under compute

        const __bf16* KsB = &Ks[buf][0];
        const __bf16* VsB = &Vs[buf][0];

        // S^T = K Q^T : st[n], lane holds P[q=w*16+lm][kv=16n+4lk+r]
        f32x4 st[4] = {};
        __builtin_amdgcn_s_setprio(1);
#pragma unroll
        for (int kk = 0; kk < 2; ++kk) {
#pragma unroll
            for (int n = 0; n < 4; ++n) {
                bf16x8 kf = *(const bf16x8*)&KsB[(kk ? o1 : o0) + n * 1024];
                st[n] = __builtin_amdgcn_mfma_f32_16x16x32_bf16(kf, qf[kk], st[n], 0, 0, 0);
            }
        }
        __builtin_amdgcn_s_setprio(0);

        // P = exp2(S) fused into fragment assembly; PV + ones-column row-sum
#pragma unroll
        for (int kk = 0; kk < 2; ++kk) {
            bf16x8 pa;
#pragma unroll
            for (int j = 0; j < 8; ++j)
                pa[j] = (__bf16)FEXP2(st[2 * kk + (j >> 2)][j & 3]);
            __builtin_amdgcn_s_setprio(1);
            o_s = __builtin_amdgcn_mfma_f32_16x16x32_bf16(pa, ones, o_s, 0, 0, 0);
#pragma unroll
            for (int dn = 0; dn < 4; ++dn) {
                bf16x8 vf = *(const bf16x8*)&VsB[(kk ? o1 : o0) + dn * 1024];
                o[dn] = __builtin_amdgcn_mfma_f32_16x16x32_bf16(pa, vf, o[dn], 0, 0, 0);
            }
            __builtin_amdgcn_s_setprio(0);
        }

        if (it + 1 < 32) { FA_WRITE(buf ^ 1); }        // lands in the other buffer
        __syncthreads();                               // one barrier per tile
    }

    // epilogue: o_s[r] holds rowsum(q = w*16 + lk*4 + r) at every lm lane
    f32x4 inv;
#pragma unroll
    for (int r = 0; r < 4; ++r) inv[r] = 1.f / o_s[r];
#pragma unroll
    for (int dn = 0; dn < 4; ++dn)
#pragma unroll
        for (int r = 0; r < 4; ++r) {
            int row = q0 + w * 16 + lk * 4 + r;
            int col = h * HS + dn * 16 + lm;
            O[(size_t)(b * SQ + row) * DD + col] = (__bf16)(o[dn][r] * inv[r]);
        }
}

extern "C" void kernel_launch(void* const* d_in, const int* in_sizes, int n_in,
                              void* d_out, int out_size, void* d_ws, size_t ws_size,
                              hipStream_t stream) {
    const float* inputs  = (const float*)d_in[0];
    const float* context = (const float*)d_in[1];
    const float* Wq = (const float*)d_in[2];
    const float* bq = (const float*)d_in[3];
    const float* Wk = (const float*)d_in[4];
    const float* bk = (const float*)d_in[5];
    const float* Wv = (const float*)d_in[6];
    const float* bv = (const float*)d_in[7];
    const float* Wo = (const float*)d_in[8];
    const float* bo = (const float*)d_in[9];
    float* out = (float*)d_out;

    char* ws = (char*)d_ws;
    const size_t SEG = (size_t)4096 * 1024 * sizeof(__bf16);  // 8 MB
    __bf16* attb = (__bf16*)(ws + 0 * SEG);   // attention output (bf16)
    __bf16* Wt   = (__bf16*)(ws + 2 * SEG);   // 4 x 1024x1024 bf16 (B-swizzled layout)
    __bf16* Qb   = (__bf16*)(ws + 3 * SEG);
    __bf16* Kbuf = (__bf16*)(ws + 4 * SEG);
    __bf16* Vtb  = (__bf16*)(ws + 5 * SEG);   // V transposed + sigma-permuted by gemm_qkv

    wtrans<<<dim3(32, 32, 4), dim3(32, 8), 0, stream>>>(Wq, Wk, Wv, Wo, Wt);

    gemm_qkv<<<dim3(16, 96), 256, 0, stream>>>(inputs, context, Wt, bq, bk, bv,
                                               Qb, Kbuf, Vtb, SCALE * LOG2E);

    flash_attn<<<dim3(16, 32), 512, 0, stream>>>(Qb, Kbuf, Vtb, attb);

    gemm_out64<<<dim3(8, 64), 256, 0, stream>>>(attb, Wt + (size_t)3 * DD * DD, bo, out);
}